// Round 11
// baseline (437.030 us; speedup 1.0000x reference)
//
#include <hip/hip_runtime.h>
#include <math.h>

#define N_NODES 15000
#define N_EDGES 40000
#define N_GRAPHS 750
#define N_TILES 938    // ceil(15000/16)
#define N_TILES_PAD 944  // multiple of 8 -> ft-sibling blocks share XCD under round-robin

typedef __attribute__((ext_vector_type(8))) short bf16x8;
typedef __attribute__((ext_vector_type(4))) float f32x4;

__device__ __forceinline__ float sigmoidf_(float x) { return 1.f / (1.f + expf(-x)); }

// round-to-nearest-even fp32 -> bf16 bits
__device__ __forceinline__ unsigned short f2bf(float v) {
    unsigned u = __float_as_uint(v);
    unsigned r = (u + 0x7FFFu + ((u >> 16) & 1u)) >> 16;
    return (unsigned short)r;
}
__device__ __forceinline__ float bf2f(unsigned short b) {
    return __uint_as_float(((unsigned)b) << 16);
}

// Apack layout (shorts): nt*2048 + kt*1024 + hilo*512 + lane*8 + j
//   value = split(node_h[nt*16 + (lane&15)][kt*32 + (lane>>4)*8 + j])

// ---------------- CSR scan ----------------
__global__ void tscan_kernel(const int* __restrict__ tcnt, int* __restrict__ tptr,
                             int* __restrict__ cursor) {
    __shared__ int buf[1024];
    int t = threadIdx.x;
    int v = (t < N_TILES) ? tcnt[t] : 0;
    buf[t] = v;
    __syncthreads();
    for (int ofs = 1; ofs < 1024; ofs <<= 1) {
        int a = (t >= ofs) ? buf[t - ofs] : 0;
        __syncthreads();
        buf[t] += a;
        __syncthreads();
    }
    int excl = buf[t] - v;
    if (t <= N_TILES_PAD) tptr[t] = excl;   // t>=938 -> excl == total
    if (t < N_TILES) cursor[t] = excl;
}

// fill edge_list + initial A-fragment pack (node_h ready after prep)
__global__ void fillpack_kernel(const int* __restrict__ src, int* __restrict__ cursor,
                                int* __restrict__ edge_list,
                                const float* __restrict__ node_h,
                                unsigned short* __restrict__ Apack) {
    int b = blockIdx.x;
    int tid = threadIdx.x;
    if (b < 157) {
        int e = b * 256 + tid;
        if (e < N_EDGES) {
            int slot = atomicAdd(&cursor[src[e] >> 4], 1);
            edge_list[slot] = e;
        }
    } else {
        int nt = b - 157;
        for (int idx = tid; idx < 1024; idx += 256) {
            int kt = idx >> 9, lane = (idx >> 3) & 63, j = idx & 7;
            int quad = lane >> 4, m = lane & 15;
            int n = nt * 16 + m;
            float v = (n < N_NODES) ? node_h[(size_t)n * 64 + kt * 32 + quad * 8 + j] : 0.f;
            unsigned short hi = f2bf(v);
            Apack[nt * 2048 + kt * 1024 + lane * 8 + j] = hi;
            Apack[nt * 2048 + kt * 1024 + 512 + lane * 8 + j] = f2bf(v - bf2f(hi));
        }
    }
}

// ---------------- fused prep mega-kernel (block-range partitioned) ----------------
// [0,3750): proj. [3750,13750): h1. [13750,14806): conv e2_W+e2_b bf16 pack (33 ct).
// [14806,14998): LSTM transposes. [14998,15094): gru weight packs. [15094,15153): gptr.
// [15153,15310): edge count (tcnt/deg).
__global__ __launch_bounds__(256)
void prep_kernel(const float* __restrict__ x, const float* __restrict__ in_W,
                 const float* __restrict__ in_b, float* __restrict__ node_h,
                 const float* __restrict__ e2b,
                 const float* __restrict__ ea, const float* __restrict__ e1_W,
                 const float* __restrict__ e1_b, float* __restrict__ h1,
                 const float* __restrict__ e2W,
                 unsigned short* __restrict__ Bhi, unsigned short* __restrict__ Blo,
                 const float* __restrict__ lWih, const float* __restrict__ lWhh,
                 const float* __restrict__ gWih, const float* __restrict__ gWhh,
                 float* __restrict__ lWihT, float* __restrict__ lWhhT,
                 unsigned short* __restrict__ gWihP, unsigned short* __restrict__ gWhhP,
                 const int* __restrict__ batch, int* __restrict__ gptr,
                 const int* __restrict__ src, const int* __restrict__ dst,
                 int* __restrict__ tcnt, float* __restrict__ deg) {
    int b = blockIdx.x;
    int tid = threadIdx.x;
    if (b < 3750) {
        __shared__ float xs[4][32];
        int n0 = b * 4;
        if (tid < 128) xs[tid >> 5][tid & 31] = x[n0 * 32 + tid];
        __syncthreads();
        int nn = tid >> 6, f = tid & 63;
        float s = in_b[f];
        #pragma unroll
        for (int i = 0; i < 32; ++i) s += xs[nn][i] * in_W[i * 64 + f];
        node_h[(size_t)(n0 + nn) * 64 + f] = fmaxf(s, 0.f);
    } else if (b < 13750) {
        __shared__ float eas[4][16];
        int e0 = (b - 3750) * 4;
        if (tid < 64) eas[tid >> 4][tid & 15] = ea[e0 * 16 + tid];
        __syncthreads();
        int nn = tid >> 6, f = tid & 63;
        float s = e1_b[f];
        #pragma unroll
        for (int i = 0; i < 16; ++i) s += eas[nn][i] * e1_W[i * 64 + f];
        h1[(size_t)(e0 + nn) * 64 + f] = fmaxf(s, 0.f);
    } else if (b < 14806) {
        // conv B pack, 33 column-tiles per ft (ct 32 = e2_b bias fold):
        // shorts idx = (((ft*33+ct)*2+kt)*64 + lane)*8 + j
        int idx = (b - 13750) * 256 + tid;           // [0, 270336)
        int j = idx & 7, lane = (idx >> 3) & 63, kt = (idx >> 9) & 1;
        int rem = idx >> 10;
        int ct = rem % 33, ft = rem / 33;
        int d = kt * 32 + ((lane >> 4) << 3) + j;
        int m = lane & 15;
        float v;
        if (ct < 32) {
            int c = ct * 16 + m;
            int kk = c >> 3, fi = c & 7;
            v = e2W[(size_t)kk * 4096 + d * 64 + ft * 8 + fi];
        } else {
            v = (m < 8) ? e2b[d * 64 + ft * 8 + m] : 0.f;
        }
        unsigned short hi = f2bf(v);
        Bhi[idx] = hi;
        Blo[idx] = f2bf(v - bf2f(hi));
    } else if (b < 14998) {
        int idx = (b - 14806) * 256 + tid;
        if (idx < 32768) {                       // lWih [256][128] -> [128][256]
            int i = idx >> 8, r = idx & 255;
            lWihT[i * 256 + r] = lWih[r * 128 + i];
        } else if (idx < 49152) {                // lWhh [256][64] -> [64][256]
            int x2 = idx - 32768; int i = x2 >> 8, r = x2 & 255;
            lWhhT[i * 256 + r] = lWhh[r * 64 + i];
        }
    } else if (b < 15094) {
        // gru MFMA B-operand packs
        int idx = (b - 14998) * 256 + tid;       // [0, 24576)
        if (idx < 12288) {
            int j = idx & 7, lane = (idx >> 3) & 63, kt = (idx >> 9) & 1, ct = idx >> 10;
            int k = kt * 32 + ((lane >> 4) << 3) + j;
            int n = ct * 16 + (lane & 15);
            float v = gWih[n * 64 + k];
            unsigned short hi = f2bf(v);
            gWihP[idx] = hi;
            gWihP[12288 + idx] = f2bf(v - bf2f(hi));
        } else {
            int i2 = idx - 12288;
            int j = i2 & 7, lane = (i2 >> 3) & 63, kt = (i2 >> 9) & 1, ct = i2 >> 10;
            int k = kt * 32 + ((lane >> 4) << 3) + j;
            int n = ct * 16 + (lane & 15);
            float v = gWhh[n * 64 + k];
            unsigned short hi = f2bf(v);
            gWhhP[i2] = hi;
            gWhhP[12288 + i2] = f2bf(v - bf2f(hi));
        }
    } else if (b < 15153) {
        int n = (b - 15094) * 256 + tid;
        if (n < N_NODES) {
            int bb = batch[n];
            int pb = (n == 0) ? -1 : batch[n - 1];
            for (int g = pb + 1; g <= bb; ++g) gptr[g] = n;
            if (n == N_NODES - 1)
                for (int g = bb + 1; g <= N_GRAPHS; ++g) gptr[g] = N_NODES;
        }
    } else {
        int e = (b - 15153) * 256 + tid;
        if (e < N_EDGES) {
            atomicAdd(&tcnt[src[e] >> 4], 1);
            atomicAdd(&deg[dst[e]], 1.f);
        }
    }
}

// ---------------- fused conv: preloaded A-frags, MFMA phase A, dual-edge scatter ----
// Phase A: 4 coalesced b128 A-frag loads (pre-split bf16, no VALU build), 33 ct
// (ct 32 = bias). One barrier total. Phase B: dual-edge per slot.
__global__ __launch_bounds__(256, 4)
void conv_kernel(const unsigned short* __restrict__ Apack, const float* __restrict__ h1,
                 const unsigned short* __restrict__ Bhi, const unsigned short* __restrict__ Blo,
                 const int* __restrict__ tptr, const int* __restrict__ edge_list,
                 const int* __restrict__ src, const int* __restrict__ dst,
                 float* __restrict__ agg) {
    __shared__ float T_lds[16 * 548];    // [node]*548 + [fi]*68 + kk ; kk 0..63 + 64=Tb
    int bid = blockIdx.x;
    int nt = bid % N_TILES_PAD, ft = bid / N_TILES_PAD;
    int n0 = nt * 16;
    int tid = threadIdx.x;
    int lane = tid & 63, wave = tid >> 6;
    int quad = lane >> 4, m = lane & 15;

    // A-fragments: pre-split, fragment-ordered -> 4 coalesced 16B loads
    const unsigned short* ap = Apack + nt * 2048 + lane * 8;
    bf16x8 ahi[2], alo[2];
    ahi[0] = *(const bf16x8*)(ap);
    alo[0] = *(const bf16x8*)(ap + 512);
    ahi[1] = *(const bf16x8*)(ap + 1024);
    alo[1] = *(const bf16x8*)(ap + 1536);

    // B-frag pointers: ct stride 1024 shorts, kt +512; wave w: ct = w, w+4, ...
    size_t base0 = (size_t)(ft * 33 + wave) * 1024 + lane * 8;
    const unsigned short* ph = Bhi + base0;
    const unsigned short* pl = Blo + base0;
    bf16x8 bh0 = *(const bf16x8*)(ph);
    bf16x8 bh1 = *(const bf16x8*)(ph + 512);
    bf16x8 bl0 = *(const bf16x8*)(pl);
    bf16x8 bl1 = *(const bf16x8*)(pl + 512);

    int nct = (wave == 0) ? 9 : 8;
    #pragma unroll 1
    for (int ci = 0; ci < nct; ++ci) {
        bf16x8 ch0 = bh0, ch1 = bh1, cl0 = bl0, cl1 = bl1;
        if (ci + 1 < nct) {
            const unsigned short* nh = ph + (size_t)(ci + 1) * 4096;
            const unsigned short* nl = pl + (size_t)(ci + 1) * 4096;
            bh0 = *(const bf16x8*)(nh);
            bh1 = *(const bf16x8*)(nh + 512);
            bl0 = *(const bf16x8*)(nl);
            bl1 = *(const bf16x8*)(nl + 512);
        }
        f32x4 accA = {0.f, 0.f, 0.f, 0.f};
        f32x4 accB = {0.f, 0.f, 0.f, 0.f};
        accA = __builtin_amdgcn_mfma_f32_16x16x32_bf16(ahi[0], ch0, accA, 0, 0, 0);
        accB = __builtin_amdgcn_mfma_f32_16x16x32_bf16(ahi[1], ch1, accB, 0, 0, 0);
        accA = __builtin_amdgcn_mfma_f32_16x16x32_bf16(alo[0], ch0, accA, 0, 0, 0);
        accB = __builtin_amdgcn_mfma_f32_16x16x32_bf16(alo[1], ch1, accB, 0, 0, 0);
        accA = __builtin_amdgcn_mfma_f32_16x16x32_bf16(ahi[0], cl0, accA, 0, 0, 0);
        accB = __builtin_amdgcn_mfma_f32_16x16x32_bf16(ahi[1], cl1, accB, 0, 0, 0);
        int ct = wave + ci * 4;
        int c = ct * 16 + m;
        int kk = c >> 3, fi = c & 7;   // ct=32: kk=64/65 (65 = harmless pad)
        #pragma unroll
        for (int r = 0; r < 4; ++r)
            T_lds[(quad * 4 + r) * 548 + fi * 68 + kk] = accA[r] + accB[r];
    }
    __syncthreads();

    // Phase B: dual-edge per slot, independent chains
    int fi = tid & 7, slot = tid >> 3;
    int te0 = tptr[nt], te1 = tptr[nt + 1];
    for (int c = te0 + slot; c < te1; c += 64) {
        int c1 = c + 32;
        bool h2 = (c1 < te1);
        int e0 = edge_list[c];
        int e1 = h2 ? edge_list[c1] : e0;
        int nn0 = src[e0] - n0, nn1 = src[e1] - n0;
        const float* h0p = h1 + (size_t)e0 * 64;
        const float* h1p = h1 + (size_t)e1 * 64;
        const float* T0 = &T_lds[nn0 * 548 + fi * 68];
        const float* T1 = &T_lds[nn1 * 548 + fi * 68];
        float p00 = T0[64], p01 = 0.f;   // Tb slot
        float p10 = T1[64], p11 = 0.f;
        #pragma unroll
        for (int k4 = 0; k4 < 64; k4 += 8) {
            float4 ha = *(const float4*)(h0p + k4);
            float4 ta = *(const float4*)(T0 + k4);
            float4 hb = *(const float4*)(h0p + k4 + 4);
            float4 tb = *(const float4*)(T0 + k4 + 4);
            float4 hc = *(const float4*)(h1p + k4);
            float4 tc = *(const float4*)(T1 + k4);
            float4 hd = *(const float4*)(h1p + k4 + 4);
            float4 td = *(const float4*)(T1 + k4 + 4);
            p00 += ha.x * ta.x + ha.y * ta.y + ha.z * ta.z + ha.w * ta.w;
            p01 += hb.x * tb.x + hb.y * tb.y + hb.z * tb.z + hb.w * tb.w;
            p10 += hc.x * tc.x + hc.y * tc.y + hc.z * tc.z + hc.w * tc.w;
            p11 += hd.x * td.x + hd.y * td.y + hd.z * td.z + hd.w * td.w;
        }
        atomicAdd(&agg[(size_t)dst[e0] * 64 + ft * 8 + fi], p00 + p01);
        if (h2) atomicAdd(&agg[(size_t)dst[e1] * 64 + ft * 8 + fi], p10 + p11);
    }
}

// ---------------- GRU as MFMA GEMM: 32 nodes/block + A-fragment pack epilogue ------
__global__ __launch_bounds__(256, 4)
void gru_kernel(float* __restrict__ node_h, float* __restrict__ agg,
                const float* __restrict__ deg, const float* __restrict__ conv_b,
                const unsigned short* __restrict__ WihP, const unsigned short* __restrict__ WhhP,
                const float* __restrict__ bih, const float* __restrict__ bhh,
                unsigned short* __restrict__ Apack, int want_pack) {
    __shared__ unsigned short m_bf[2][32][72];
    __shared__ unsigned short h_bf[2][32][72];
    __shared__ float h_s[32][68];
    __shared__ float hn_s[32][68];
    int n0 = blockIdx.x * 32;
    int tid = threadIdx.x;
    int lane = tid & 63, w = tid >> 6;
    int quad = lane >> 4, m16 = lane & 15;

    for (int i = tid; i < 2048; i += 256) {
        int c = i >> 6, f = i & 63;
        int n = n0 + c;
        float mv = 0.f, hv = 0.f;
        if (n < N_NODES) {
            float dg = fmaxf(deg[n], 1.f);
            mv = fmaxf(agg[(size_t)n * 64 + f] / dg + conv_b[f], 0.f);
            agg[(size_t)n * 64 + f] = 0.f;
            hv = node_h[(size_t)n * 64 + f];
        }
        unsigned short mh = f2bf(mv);
        m_bf[0][c][f] = mh; m_bf[1][c][f] = f2bf(mv - bf2f(mh));
        unsigned short hh = f2bf(hv);
        h_bf[0][c][f] = hh; h_bf[1][c][f] = f2bf(hv - bf2f(hh));
        h_s[c][f] = hv;
    }

    bf16x8 Bi[3][2][2], Bh[3][2][2];
    #pragma unroll
    for (int g = 0; g < 3; ++g)
        #pragma unroll
        for (int kt = 0; kt < 2; ++kt) {
            size_t base = ((size_t)((g * 4 + w) * 2 + kt) * 64 + lane) * 8;
            Bi[g][kt][0] = *(const bf16x8*)(WihP + base);
            Bi[g][kt][1] = *(const bf16x8*)(WihP + 12288 + base);
            Bh[g][kt][0] = *(const bf16x8*)(WhhP + base);
            Bh[g][kt][1] = *(const bf16x8*)(WhhP + 12288 + base);
        }
    int f = w * 16 + m16;
    float br_i = bih[f],       br_h = bhh[f];
    float bz_i = bih[64 + f],  bz_h = bhh[64 + f];
    float bn_i = bih[128 + f], bn_h = bhh[128 + f];
    __syncthreads();

    #pragma unroll 1
    for (int mt = 0; mt < 2; ++mt) {
        bf16x8 Am[2][2], Ah[2][2];
        #pragma unroll
        for (int kt = 0; kt < 2; ++kt) {
            Am[kt][0] = *(const bf16x8*)(&m_bf[0][mt * 16 + m16][kt * 32 + quad * 8]);
            Am[kt][1] = *(const bf16x8*)(&m_bf[1][mt * 16 + m16][kt * 32 + quad * 8]);
            Ah[kt][0] = *(const bf16x8*)(&h_bf[0][mt * 16 + m16][kt * 32 + quad * 8]);
            Ah[kt][1] = *(const bf16x8*)(&h_bf[1][mt * 16 + m16][kt * 32 + quad * 8]);
        }
        f32x4 ai[3], ah[3];
        #pragma unroll
        for (int g = 0; g < 3; ++g) { ai[g] = (f32x4){0.f,0.f,0.f,0.f}; ah[g] = (f32x4){0.f,0.f,0.f,0.f}; }
        #pragma unroll
        for (int g = 0; g < 3; ++g)
            #pragma unroll
            for (int kt = 0; kt < 2; ++kt) {
                ai[g] = __builtin_amdgcn_mfma_f32_16x16x32_bf16(Am[kt][0], Bi[g][kt][0], ai[g], 0, 0, 0);
                ai[g] = __builtin_amdgcn_mfma_f32_16x16x32_bf16(Am[kt][0], Bi[g][kt][1], ai[g], 0, 0, 0);
                ai[g] = __builtin_amdgcn_mfma_f32_16x16x32_bf16(Am[kt][1], Bi[g][kt][0], ai[g], 0, 0, 0);
                ah[g] = __builtin_amdgcn_mfma_f32_16x16x32_bf16(Ah[kt][0], Bh[g][kt][0], ah[g], 0, 0, 0);
                ah[g] = __builtin_amdgcn_mfma_f32_16x16x32_bf16(Ah[kt][0], Bh[g][kt][1], ah[g], 0, 0, 0);
                ah[g] = __builtin_amdgcn_mfma_f32_16x16x32_bf16(Ah[kt][1], Bh[g][kt][0], ah[g], 0, 0, 0);
            }
        #pragma unroll
        for (int r = 0; r < 4; ++r) {
            int node = mt * 16 + quad * 4 + r;
            float rr = sigmoidf_(ai[0][r] + br_i + ah[0][r] + br_h);
            float zz = sigmoidf_(ai[1][r] + bz_i + ah[1][r] + bz_h);
            float n2 = tanhf(ai[2][r] + bn_i + rr * (ah[2][r] + bn_h));
            float hnew = (1.f - zz) * n2 + zz * h_s[node][f];
            int n = n0 + node;
            if (n < N_NODES) node_h[(size_t)n * 64 + f] = hnew;
            hn_s[node][f] = hnew;
        }
    }
    if (want_pack) {
        __syncthreads();
        // re-gather hnew into conv A-fragment order for tiles 2*bid, 2*bid+1
        for (int idx = tid; idx < 2048; idx += 256) {
            int tt = idx >> 10, r2 = idx & 1023;
            int kt = r2 >> 9, ln = (r2 >> 3) & 63, j = r2 & 7;
            int q2 = ln >> 4, mm = ln & 15;
            float v = hn_s[tt * 16 + mm][kt * 32 + q2 * 8 + j];
            unsigned short hi = f2bf(v);
            size_t base = (size_t)(blockIdx.x * 2 + tt) * 2048 + kt * 1024 + ln * 8 + j;
            Apack[base] = hi;
            Apack[base + 512] = f2bf(v - bf2f(hi));
        }
    }
}

// ---------------- Set2Set (3 steps) + output MLP, 128 threads (2 waves) per graph ---
__global__ __launch_bounds__(128)
void s2s_kernel(const float* __restrict__ node_h, const int* __restrict__ gptr,
                const float* __restrict__ WihT, const float* __restrict__ WhhT,
                const float* __restrict__ bih, const float* __restrict__ bhh,
                const float* __restrict__ o1W, const float* __restrict__ o1b,
                const float* __restrict__ o2W, const float* __restrict__ o2b,
                float* __restrict__ z) {
    int g = blockIdx.x, tid = threadIdx.x;
    int f = tid & 63, half = tid >> 6;
    __shared__ float qs[128], hs[64], q[64], wts[128], gvs[4][64], racc_s[2][64];
    __shared__ float mred[2], sred[2], ored[2];
    if (half == 0) { qs[f] = 0.f; qs[64 + f] = 0.f; hs[f] = 0.f; }
    float c_t = 0.f;
    int nbeg = gptr[g], nend = gptr[g + 1];
    __syncthreads();
    for (int st = 0; st < 3; ++st) {
        #pragma unroll
        for (int gg = 0; gg < 2; ++gg) {
            int gate = half * 2 + gg;
            int row = gate * 64 + f;
            float s = bih[row] + bhh[row];
            #pragma unroll 8
            for (int i = 0; i < 128; ++i) s += qs[i] * WihT[i * 256 + row];
            #pragma unroll 8
            for (int i = 0; i < 64; ++i) s += hs[i] * WhhT[i * 256 + row];
            gvs[gate][f] = s;
        }
        __syncthreads();
        if (half == 0) {
            float c = sigmoidf_(gvs[1][f]) * c_t + sigmoidf_(gvs[0][f]) * tanhf(gvs[2][f]);
            float hn = sigmoidf_(gvs[3][f]) * tanhf(c);
            c_t = c;
            hs[f] = hn; q[f] = hn;
        }
        __syncthreads();
        float rm = -INFINITY, rs = 0.f, raccl = 0.f;
        for (int base = nbeg; base < nend; base += 128) {
            int n = base + tid;
            float e = -INFINITY;
            if (n < nend) {
                float s = 0.f;
                #pragma unroll 8
                for (int ff = 0; ff < 64; ++ff) s += node_h[(size_t)n * 64 + ff] * q[ff];
                e = s;
            }
            float cm = e;
            #pragma unroll
            for (int o = 32; o > 0; o >>= 1) cm = fmaxf(cm, __shfl_down(cm, o));
            if ((tid & 63) == 0) mred[half] = cm;
            __syncthreads();
            float bm = fmaxf(mred[0], mred[1]);
            float nm = fmaxf(rm, bm);
            float scale = (rm == -INFINITY) ? 0.f : expf(rm - nm);
            float wv = (n < nend) ? expf(e - nm) : 0.f;
            wts[tid] = wv;
            float cs = wv;
            #pragma unroll
            for (int o = 32; o > 0; o >>= 1) cs += __shfl_down(cs, o);
            if ((tid & 63) == 0) sred[half] = cs;
            __syncthreads();
            float bs = sred[0] + sred[1];
            float na = raccl * scale;
            int cnt2 = min(128, nend - base);
            int l0 = half * 64, l1 = min(l0 + 64, cnt2);
            for (int l = l0; l < l1; ++l) na += wts[l] * node_h[(size_t)(base + l) * 64 + f];
            raccl = na;
            rs = rs * scale + bs;
            rm = nm;
            __syncthreads();
        }
        racc_s[half][f] = raccl;
        __syncthreads();
        if (half == 0) {
            float r = (nend > nbeg) ? (racc_s[0][f] + racc_s[1][f]) / rs : 0.f;
            qs[f] = q[f];
            qs[64 + f] = r;
        }
        __syncthreads();
    }
    float sA = o1b[tid];
    #pragma unroll 8
    for (int i = 0; i < 128; ++i) sA += qs[i] * o1W[i * 128 + tid];
    float red = fmaxf(sA, 0.f) * o2W[tid];
    #pragma unroll
    for (int o = 32; o > 0; o >>= 1) red += __shfl_down(red, o);
    if ((tid & 63) == 0) ored[half] = red;
    __syncthreads();
    if (tid == 0) z[g] = ored[0] + ored[1] + o2b[0];
}

extern "C" void kernel_launch(void* const* d_in, const int* in_sizes, int n_in,
                              void* d_out, int out_size, void* d_ws, size_t ws_size,
                              hipStream_t stream) {
    const float* x         = (const float*)d_in[0];
    const float* edge_attr = (const float*)d_in[1];
    const int*   ei        = (const int*)d_in[2];
    const int*   batch     = (const int*)d_in[3];
    const float* in_W      = (const float*)d_in[4];
    const float* in_b      = (const float*)d_in[5];
    const float* e1_W      = (const float*)d_in[6];
    const float* e1_b      = (const float*)d_in[7];
    const float* e2_W      = (const float*)d_in[8];
    const float* e2_b      = (const float*)d_in[9];
    const float* conv_b    = (const float*)d_in[10];
    const float* gWih      = (const float*)d_in[11];
    const float* gWhh      = (const float*)d_in[12];
    const float* gbih      = (const float*)d_in[13];
    const float* gbhh      = (const float*)d_in[14];
    const float* lWih      = (const float*)d_in[15];
    const float* lWhh      = (const float*)d_in[16];
    const float* lbih      = (const float*)d_in[17];
    const float* lbhh      = (const float*)d_in[18];
    const float* o1W       = (const float*)d_in[19];
    const float* o1b       = (const float*)d_in[20];
    const float* o2W       = (const float*)d_in[21];
    const float* o2b       = (const float*)d_in[22];
    const int* src = ei;
    const int* dst = ei + N_EDGES;
    float* z = (float*)d_out;

    char* ws = (char*)d_ws;
    size_t off = 0;
    auto alloc = [&](size_t bytes) {
        void* p = ws + off;
        off = (off + bytes + 255) & ~(size_t)255;
        return p;
    };
    float* node_h   = (float*)alloc((size_t)N_NODES * 64 * 4);
    float* agg      = (float*)alloc((size_t)N_NODES * 64 * 4);
    float* h1       = (float*)alloc((size_t)N_EDGES * 64 * 4);
    unsigned short* Bhi = (unsigned short*)alloc((size_t)270336 * 2);
    unsigned short* Blo = (unsigned short*)alloc((size_t)270336 * 2);
    unsigned short* Apack = (unsigned short*)alloc((size_t)N_TILES_PAD * 2048 * 2);
    float* lWihT    = (float*)alloc(128 * 256 * 4);
    float* lWhhT    = (float*)alloc(64 * 256 * 4);
    unsigned short* gWihP = (unsigned short*)alloc(24576 * 2);
    unsigned short* gWhhP = (unsigned short*)alloc(24576 * 2);
    float* deg      = (float*)alloc(N_NODES * 4);       // deg,tcnt adjacent (one memset)
    int*   tcnt     = (int*)alloc((N_TILES + 2) * 4);
    int*   tcursor  = (int*)alloc((N_TILES + 2) * 4);
    int*   tptr     = (int*)alloc((N_TILES_PAD + 2) * 4);
    int*   edge_list= (int*)alloc(N_EDGES * 4);
    int*   gptr     = (int*)alloc((N_GRAPHS + 1) * 4);

    size_t degpad = ((size_t)N_NODES * 4 + 255) & ~(size_t)255;
    hipMemsetAsync(deg, 0, degpad + (N_TILES + 2) * 4, stream);   // deg + tcnt
    hipMemsetAsync(agg, 0, (size_t)N_NODES * 64 * 4, stream);     // once; gru re-zeroes

    prep_kernel<<<15310, 256, 0, stream>>>(x, in_W, in_b, node_h, e2_b,
                                           edge_attr, e1_W, e1_b, h1,
                                           e2_W, Bhi, Blo,
                                           lWih, lWhh, gWih, gWhh,
                                           lWihT, lWhhT, gWihP, gWhhP,
                                           batch, gptr, src, dst, tcnt, deg);
    tscan_kernel<<<1, 1024, 0, stream>>>(tcnt, tptr, tcursor);
    fillpack_kernel<<<157 + N_TILES_PAD, 256, 0, stream>>>(src, tcursor, edge_list,
                                                           node_h, Apack);

    for (int it = 0; it < 3; ++it) {
        conv_kernel<<<N_TILES_PAD * 8, 256, 0, stream>>>(Apack, h1, Bhi, Blo,
                                                         tptr, edge_list, src, dst, agg);
        gru_kernel<<<469, 256, 0, stream>>>(node_h, agg, deg, conv_b,
                                            gWihP, gWhhP, gbih, gbhh,
                                            Apack, (it < 2) ? 1 : 0);
    }
    s2s_kernel<<<N_GRAPHS, 128, 0, stream>>>(node_h, gptr, lWihT, lWhhT, lbih, lbhh,
                                             o1W, o1b, o2W, o2b, z);
}

// Round 12
// 430.340 us; speedup vs baseline: 1.0155x; 1.0155x over previous
//
#include <hip/hip_runtime.h>
#include <math.h>

#define N_NODES 15000
#define N_EDGES 40000
#define N_GRAPHS 750
#define N_TILES 938    // ceil(15000/16)
#define N_TILES_PAD 944  // multiple of 8 -> ft-sibling blocks share XCD under round-robin

typedef __attribute__((ext_vector_type(8))) short bf16x8;
typedef __attribute__((ext_vector_type(4))) float f32x4;

__device__ __forceinline__ float sigmoidf_(float x) { return 1.f / (1.f + expf(-x)); }

// round-to-nearest-even fp32 -> bf16 bits
__device__ __forceinline__ unsigned short f2bf(float v) {
    unsigned u = __float_as_uint(v);
    unsigned r = (u + 0x7FFFu + ((u >> 16) & 1u)) >> 16;
    return (unsigned short)r;
}
__device__ __forceinline__ float bf2f(unsigned short b) {
    return __uint_as_float(((unsigned)b) << 16);
}

// Apack layout (shorts): nt*2048 + kt*1024 + hilo*512 + lane*8 + j

// ---------------- CSR scan ----------------
__global__ void tscan_kernel(const int* __restrict__ tcnt, int* __restrict__ tptr,
                             int* __restrict__ cursor) {
    __shared__ int buf[1024];
    int t = threadIdx.x;
    int v = (t < N_TILES) ? tcnt[t] : 0;
    buf[t] = v;
    __syncthreads();
    for (int ofs = 1; ofs < 1024; ofs <<= 1) {
        int a = (t >= ofs) ? buf[t - ofs] : 0;
        __syncthreads();
        buf[t] += a;
        __syncthreads();
    }
    int excl = buf[t] - v;
    if (t <= N_TILES_PAD) tptr[t] = excl;   // t>=938 -> excl == total
    if (t < N_TILES) cursor[t] = excl;
}

// fill edge_list + initial A-fragment pack (node_h ready after prep)
__global__ void fillpack_kernel(const int* __restrict__ src, int* __restrict__ cursor,
                                int* __restrict__ edge_list,
                                const float* __restrict__ node_h,
                                unsigned short* __restrict__ Apack) {
    int b = blockIdx.x;
    int tid = threadIdx.x;
    if (b < 157) {
        int e = b * 256 + tid;
        if (e < N_EDGES) {
            int slot = atomicAdd(&cursor[src[e] >> 4], 1);
            edge_list[slot] = e;
        }
    } else {
        int nt = b - 157;
        for (int idx = tid; idx < 1024; idx += 256) {
            int kt = idx >> 9, lane = (idx >> 3) & 63, j = idx & 7;
            int quad = lane >> 4, m = lane & 15;
            int n = nt * 16 + m;
            float v = (n < N_NODES) ? node_h[(size_t)n * 64 + kt * 32 + quad * 8 + j] : 0.f;
            unsigned short hi = f2bf(v);
            Apack[nt * 2048 + kt * 1024 + lane * 8 + j] = hi;
            Apack[nt * 2048 + kt * 1024 + 512 + lane * 8 + j] = f2bf(v - bf2f(hi));
        }
    }
}

// ---------------- fused prep mega-kernel (block-range partitioned, consolidated) ----
// [0,938): proj (16 nodes/block). [938,2188): h1 (32 edges/block).
// [2188,3244): conv e2_W+e2_b bf16 pack (33 ct). [3244,3436): LSTM transposes.
// [3436,3532): gru weight packs. [3532,3591): gptr. [3591,3748): edge count.
__global__ __launch_bounds__(256)
void prep_kernel(const float* __restrict__ x, const float* __restrict__ in_W,
                 const float* __restrict__ in_b, float* __restrict__ node_h,
                 const float* __restrict__ e2b,
                 const float* __restrict__ ea, const float* __restrict__ e1_W,
                 const float* __restrict__ e1_b, float* __restrict__ h1,
                 const float* __restrict__ e2W,
                 unsigned short* __restrict__ Bhi, unsigned short* __restrict__ Blo,
                 const float* __restrict__ lWih, const float* __restrict__ lWhh,
                 const float* __restrict__ gWih, const float* __restrict__ gWhh,
                 float* __restrict__ lWihT, float* __restrict__ lWhhT,
                 unsigned short* __restrict__ gWihP, unsigned short* __restrict__ gWhhP,
                 const int* __restrict__ batch, int* __restrict__ gptr,
                 const int* __restrict__ src, const int* __restrict__ dst,
                 int* __restrict__ tcnt, float* __restrict__ deg) {
    int b = blockIdx.x;
    int tid = threadIdx.x;
    if (b < 938) {
        __shared__ float xs[4][32];
        int n0 = b * 16;
        for (int g2 = 0; g2 < 4; ++g2) {
            int nb = n0 + g2 * 4;
            __syncthreads();
            if (tid < 128) {
                int xi = nb * 32 + tid;
                xs[tid >> 5][tid & 31] = (xi < N_NODES * 32) ? x[xi] : 0.f;
            }
            __syncthreads();
            int nn = tid >> 6, f = tid & 63;
            float s = in_b[f];
            #pragma unroll
            for (int i = 0; i < 32; ++i) s += xs[nn][i] * in_W[i * 64 + f];
            if (nb + nn < N_NODES) node_h[(size_t)(nb + nn) * 64 + f] = fmaxf(s, 0.f);
        }
    } else if (b < 2188) {
        __shared__ float eas[4][16];
        int e0 = (b - 938) * 32;
        for (int g2 = 0; g2 < 8; ++g2) {
            int eb = e0 + g2 * 4;
            __syncthreads();
            if (tid < 64) eas[tid >> 4][tid & 15] = ea[eb * 16 + tid];
            __syncthreads();
            int nn = tid >> 6, f = tid & 63;
            float s = e1_b[f];
            #pragma unroll
            for (int i = 0; i < 16; ++i) s += eas[nn][i] * e1_W[i * 64 + f];
            h1[(size_t)(eb + nn) * 64 + f] = fmaxf(s, 0.f);
        }
    } else if (b < 3244) {
        // conv B pack, 33 column-tiles per ft (ct 32 = e2_b bias fold):
        // shorts idx = (((ft*33+ct)*2+kt)*64 + lane)*8 + j
        int idx = (b - 2188) * 256 + tid;            // [0, 270336)
        int j = idx & 7, lane = (idx >> 3) & 63, kt = (idx >> 9) & 1;
        int rem = idx >> 10;
        int ct = rem % 33, ft = rem / 33;
        int d = kt * 32 + ((lane >> 4) << 3) + j;
        int m = lane & 15;
        float v;
        if (ct < 32) {
            int c = ct * 16 + m;
            int kk = c >> 3, fi = c & 7;
            v = e2W[(size_t)kk * 4096 + d * 64 + ft * 8 + fi];
        } else {
            v = (m < 8) ? e2b[d * 64 + ft * 8 + m] : 0.f;
        }
        unsigned short hi = f2bf(v);
        Bhi[idx] = hi;
        Blo[idx] = f2bf(v - bf2f(hi));
    } else if (b < 3436) {
        int idx = (b - 3244) * 256 + tid;
        if (idx < 32768) {                       // lWih [256][128] -> [128][256]
            int i = idx >> 8, r = idx & 255;
            lWihT[i * 256 + r] = lWih[r * 128 + i];
        } else if (idx < 49152) {                // lWhh [256][64] -> [64][256]
            int x2 = idx - 32768; int i = x2 >> 8, r = x2 & 255;
            lWhhT[i * 256 + r] = lWhh[r * 64 + i];
        }
    } else if (b < 3532) {
        // gru MFMA B-operand packs
        int idx = (b - 3436) * 256 + tid;        // [0, 24576)
        if (idx < 12288) {
            int j = idx & 7, lane = (idx >> 3) & 63, kt = (idx >> 9) & 1, ct = idx >> 10;
            int k = kt * 32 + ((lane >> 4) << 3) + j;
            int n = ct * 16 + (lane & 15);
            float v = gWih[n * 64 + k];
            unsigned short hi = f2bf(v);
            gWihP[idx] = hi;
            gWihP[12288 + idx] = f2bf(v - bf2f(hi));
        } else {
            int i2 = idx - 12288;
            int j = i2 & 7, lane = (i2 >> 3) & 63, kt = (i2 >> 9) & 1, ct = i2 >> 10;
            int k = kt * 32 + ((lane >> 4) << 3) + j;
            int n = ct * 16 + (lane & 15);
            float v = gWhh[n * 64 + k];
            unsigned short hi = f2bf(v);
            gWhhP[i2] = hi;
            gWhhP[12288 + i2] = f2bf(v - bf2f(hi));
        }
    } else if (b < 3591) {
        int n = (b - 3532) * 256 + tid;
        if (n < N_NODES) {
            int bb = batch[n];
            int pb = (n == 0) ? -1 : batch[n - 1];
            for (int g = pb + 1; g <= bb; ++g) gptr[g] = n;
            if (n == N_NODES - 1)
                for (int g = bb + 1; g <= N_GRAPHS; ++g) gptr[g] = N_NODES;
        }
    } else {
        int e = (b - 3591) * 256 + tid;
        if (e < N_EDGES) {
            atomicAdd(&tcnt[src[e] >> 4], 1);
            atomicAdd(&deg[dst[e]], 1.f);
        }
    }
}

// ---------------- fused conv: edge-chain prefetch + MFMA phase A + peeled scatter ---
// The phase-B pointer chase (edge_list -> src/dst -> h1) is issued BEFORE the MFMA
// loop so its latency overlaps phase A; the first (usually only) phase-B round is
// peeled to consume the prefetched registers.
__global__ __launch_bounds__(256, 4)
void conv_kernel(const unsigned short* __restrict__ Apack, const float* __restrict__ h1,
                 const unsigned short* __restrict__ Bhi, const unsigned short* __restrict__ Blo,
                 const int* __restrict__ tptr, const int* __restrict__ edge_list,
                 const int* __restrict__ src, const int* __restrict__ dst,
                 float* __restrict__ agg) {
    __shared__ float T_lds[16 * 548];    // [node]*548 + [fi]*68 + kk ; kk 0..63 + 64=Tb
    int bid = blockIdx.x;
    int nt = bid % N_TILES_PAD, ft = bid / N_TILES_PAD;
    int n0 = nt * 16;
    int tid = threadIdx.x;
    int lane = tid & 63, wave = tid >> 6;
    int quad = lane >> 4, m = lane & 15;

    // ---- phase-B prefetch (issues early; consumed after barrier) ----
    int te0 = tptr[nt], te1 = tptr[nt + 1];
    int fi = tid & 7, slot = tid >> 3;
    int cA = te0 + slot, cB = cA + 32;
    int eA = (cA < te1) ? edge_list[cA] : -1;
    int eB = (cB < te1) ? edge_list[cB] : -1;
    int sA_ = 0, dA_ = 0, sB_ = 0, dB_ = 0;
    float4 pa0 = make_float4(0.f, 0.f, 0.f, 0.f), pa1 = pa0, pb0 = pa0, pb1 = pa0;
    if (eA >= 0) {
        sA_ = src[eA]; dA_ = dst[eA];
        pa0 = *(const float4*)(h1 + (size_t)eA * 64);
        pa1 = *(const float4*)(h1 + (size_t)eA * 64 + 4);
    }
    if (eB >= 0) {
        sB_ = src[eB]; dB_ = dst[eB];
        pb0 = *(const float4*)(h1 + (size_t)eB * 64);
        pb1 = *(const float4*)(h1 + (size_t)eB * 64 + 4);
    }

    // ---- phase A: pre-split A-frags, MFMA over 33 ct ----
    const unsigned short* ap = Apack + nt * 2048 + lane * 8;
    bf16x8 ahi[2], alo[2];
    ahi[0] = *(const bf16x8*)(ap);
    alo[0] = *(const bf16x8*)(ap + 512);
    ahi[1] = *(const bf16x8*)(ap + 1024);
    alo[1] = *(const bf16x8*)(ap + 1536);

    size_t base0 = (size_t)(ft * 33 + wave) * 1024 + lane * 8;
    const unsigned short* ph = Bhi + base0;
    const unsigned short* pl = Blo + base0;
    bf16x8 bh0 = *(const bf16x8*)(ph);
    bf16x8 bh1 = *(const bf16x8*)(ph + 512);
    bf16x8 bl0 = *(const bf16x8*)(pl);
    bf16x8 bl1 = *(const bf16x8*)(pl + 512);

    int nct = (wave == 0) ? 9 : 8;
    #pragma unroll 1
    for (int ci = 0; ci < nct; ++ci) {
        bf16x8 ch0 = bh0, ch1 = bh1, cl0 = bl0, cl1 = bl1;
        if (ci + 1 < nct) {
            const unsigned short* nh = ph + (size_t)(ci + 1) * 4096;
            const unsigned short* nl = pl + (size_t)(ci + 1) * 4096;
            bh0 = *(const bf16x8*)(nh);
            bh1 = *(const bf16x8*)(nh + 512);
            bl0 = *(const bf16x8*)(nl);
            bl1 = *(const bf16x8*)(nl + 512);
        }
        f32x4 accA = {0.f, 0.f, 0.f, 0.f};
        f32x4 accB = {0.f, 0.f, 0.f, 0.f};
        accA = __builtin_amdgcn_mfma_f32_16x16x32_bf16(ahi[0], ch0, accA, 0, 0, 0);
        accB = __builtin_amdgcn_mfma_f32_16x16x32_bf16(ahi[1], ch1, accB, 0, 0, 0);
        accA = __builtin_amdgcn_mfma_f32_16x16x32_bf16(alo[0], ch0, accA, 0, 0, 0);
        accB = __builtin_amdgcn_mfma_f32_16x16x32_bf16(alo[1], ch1, accB, 0, 0, 0);
        accA = __builtin_amdgcn_mfma_f32_16x16x32_bf16(ahi[0], cl0, accA, 0, 0, 0);
        accB = __builtin_amdgcn_mfma_f32_16x16x32_bf16(ahi[1], cl1, accB, 0, 0, 0);
        int ct = wave + ci * 4;
        int c = ct * 16 + m;
        int kk = c >> 3, fo = c & 7;   // ct=32: kk=64/65 (65 = harmless pad)
        #pragma unroll
        for (int r = 0; r < 4; ++r)
            T_lds[(quad * 4 + r) * 548 + fo * 68 + kk] = accA[r] + accB[r];
    }
    __syncthreads();

    // ---- phase B: peeled first round (prefetched), then rare remainder ----
    if (eA >= 0) {
        int nn0 = sA_ - n0;
        int nn1 = (eB >= 0 ? sB_ : sA_) - n0;
        const float* h0p = h1 + (size_t)eA * 64;
        const float* h1p = h1 + (size_t)(eB >= 0 ? eB : eA) * 64;
        const float* T0 = &T_lds[nn0 * 548 + fi * 68];
        const float* T1 = &T_lds[nn1 * 548 + fi * 68];
        float p00 = T0[64], p01 = 0.f, p10 = T1[64], p11 = 0.f;
        {   // k4 = 0 from prefetched registers
            float4 ta = *(const float4*)(T0);
            float4 tb = *(const float4*)(T0 + 4);
            float4 tc = *(const float4*)(T1);
            float4 td = *(const float4*)(T1 + 4);
            p00 += pa0.x * ta.x + pa0.y * ta.y + pa0.z * ta.z + pa0.w * ta.w;
            p01 += pa1.x * tb.x + pa1.y * tb.y + pa1.z * tb.z + pa1.w * tb.w;
            p10 += pb0.x * tc.x + pb0.y * tc.y + pb0.z * tc.z + pb0.w * tc.w;
            p11 += pb1.x * td.x + pb1.y * td.y + pb1.z * td.z + pb1.w * td.w;
        }
        #pragma unroll
        for (int k4 = 8; k4 < 64; k4 += 8) {
            float4 ha = *(const float4*)(h0p + k4);
            float4 ta = *(const float4*)(T0 + k4);
            float4 hb = *(const float4*)(h0p + k4 + 4);
            float4 tb = *(const float4*)(T0 + k4 + 4);
            float4 hc = *(const float4*)(h1p + k4);
            float4 tc = *(const float4*)(T1 + k4);
            float4 hd = *(const float4*)(h1p + k4 + 4);
            float4 td = *(const float4*)(T1 + k4 + 4);
            p00 += ha.x * ta.x + ha.y * ta.y + ha.z * ta.z + ha.w * ta.w;
            p01 += hb.x * tb.x + hb.y * tb.y + hb.z * tb.z + hb.w * tb.w;
            p10 += hc.x * tc.x + hc.y * tc.y + hc.z * tc.z + hc.w * tc.w;
            p11 += hd.x * td.x + hd.y * td.y + hd.z * td.z + hd.w * td.w;
        }
        atomicAdd(&agg[(size_t)dA_ * 64 + ft * 8 + fi], p00 + p01);
        if (eB >= 0) atomicAdd(&agg[(size_t)dB_ * 64 + ft * 8 + fi], p10 + p11);
    }
    for (int c = cA + 64; c < te1; c += 64) {
        int c1 = c + 32;
        bool h2 = (c1 < te1);
        int e0 = edge_list[c];
        int e1 = h2 ? edge_list[c1] : e0;
        int nn0 = src[e0] - n0, nn1 = src[e1] - n0;
        const float* h0p = h1 + (size_t)e0 * 64;
        const float* h1p = h1 + (size_t)e1 * 64;
        const float* T0 = &T_lds[nn0 * 548 + fi * 68];
        const float* T1 = &T_lds[nn1 * 548 + fi * 68];
        float p00 = T0[64], p01 = 0.f, p10 = T1[64], p11 = 0.f;
        #pragma unroll
        for (int k4 = 0; k4 < 64; k4 += 8) {
            float4 ha = *(const float4*)(h0p + k4);
            float4 ta = *(const float4*)(T0 + k4);
            float4 hb = *(const float4*)(h0p + k4 + 4);
            float4 tb = *(const float4*)(T0 + k4 + 4);
            float4 hc = *(const float4*)(h1p + k4);
            float4 tc = *(const float4*)(T1 + k4);
            float4 hd = *(const float4*)(h1p + k4 + 4);
            float4 td = *(const float4*)(T1 + k4 + 4);
            p00 += ha.x * ta.x + ha.y * ta.y + ha.z * ta.z + ha.w * ta.w;
            p01 += hb.x * tb.x + hb.y * tb.y + hb.z * tb.z + hb.w * tb.w;
            p10 += hc.x * tc.x + hc.y * tc.y + hc.z * tc.z + hc.w * tc.w;
            p11 += hd.x * td.x + hd.y * td.y + hd.z * td.z + hd.w * td.w;
        }
        atomicAdd(&agg[(size_t)dst[e0] * 64 + ft * 8 + fi], p00 + p01);
        if (h2) atomicAdd(&agg[(size_t)dst[e1] * 64 + ft * 8 + fi], p10 + p11);
    }
}

// ---------------- GRU as MFMA GEMM: 32 nodes/block + A-fragment pack epilogue ------
__global__ __launch_bounds__(256, 4)
void gru_kernel(float* __restrict__ node_h, float* __restrict__ agg,
                const float* __restrict__ deg, const float* __restrict__ conv_b,
                const unsigned short* __restrict__ WihP, const unsigned short* __restrict__ WhhP,
                const float* __restrict__ bih, const float* __restrict__ bhh,
                unsigned short* __restrict__ Apack, int want_pack) {
    __shared__ unsigned short m_bf[2][32][72];
    __shared__ unsigned short h_bf[2][32][72];
    __shared__ float h_s[32][68];
    __shared__ float hn_s[32][68];
    int n0 = blockIdx.x * 32;
    int tid = threadIdx.x;
    int lane = tid & 63, w = tid >> 6;
    int quad = lane >> 4, m16 = lane & 15;

    for (int i = tid; i < 2048; i += 256) {
        int c = i >> 6, f = i & 63;
        int n = n0 + c;
        float mv = 0.f, hv = 0.f;
        if (n < N_NODES) {
            float dg = fmaxf(deg[n], 1.f);
            mv = fmaxf(agg[(size_t)n * 64 + f] / dg + conv_b[f], 0.f);
            agg[(size_t)n * 64 + f] = 0.f;
            hv = node_h[(size_t)n * 64 + f];
        }
        unsigned short mh = f2bf(mv);
        m_bf[0][c][f] = mh; m_bf[1][c][f] = f2bf(mv - bf2f(mh));
        unsigned short hh = f2bf(hv);
        h_bf[0][c][f] = hh; h_bf[1][c][f] = f2bf(hv - bf2f(hh));
        h_s[c][f] = hv;
    }

    bf16x8 Bi[3][2][2], Bh[3][2][2];
    #pragma unroll
    for (int g = 0; g < 3; ++g)
        #pragma unroll
        for (int kt = 0; kt < 2; ++kt) {
            size_t base = ((size_t)((g * 4 + w) * 2 + kt) * 64 + lane) * 8;
            Bi[g][kt][0] = *(const bf16x8*)(WihP + base);
            Bi[g][kt][1] = *(const bf16x8*)(WihP + 12288 + base);
            Bh[g][kt][0] = *(const bf16x8*)(WhhP + base);
            Bh[g][kt][1] = *(const bf16x8*)(WhhP + 12288 + base);
        }
    int f = w * 16 + m16;
    float br_i = bih[f],       br_h = bhh[f];
    float bz_i = bih[64 + f],  bz_h = bhh[64 + f];
    float bn_i = bih[128 + f], bn_h = bhh[128 + f];
    __syncthreads();

    #pragma unroll 1
    for (int mt = 0; mt < 2; ++mt) {
        bf16x8 Am[2][2], Ah[2][2];
        #pragma unroll
        for (int kt = 0; kt < 2; ++kt) {
            Am[kt][0] = *(const bf16x8*)(&m_bf[0][mt * 16 + m16][kt * 32 + quad * 8]);
            Am[kt][1] = *(const bf16x8*)(&m_bf[1][mt * 16 + m16][kt * 32 + quad * 8]);
            Ah[kt][0] = *(const bf16x8*)(&h_bf[0][mt * 16 + m16][kt * 32 + quad * 8]);
            Ah[kt][1] = *(const bf16x8*)(&h_bf[1][mt * 16 + m16][kt * 32 + quad * 8]);
        }
        f32x4 ai[3], ah[3];
        #pragma unroll
        for (int g = 0; g < 3; ++g) { ai[g] = (f32x4){0.f,0.f,0.f,0.f}; ah[g] = (f32x4){0.f,0.f,0.f,0.f}; }
        #pragma unroll
        for (int g = 0; g < 3; ++g)
            #pragma unroll
            for (int kt = 0; kt < 2; ++kt) {
                ai[g] = __builtin_amdgcn_mfma_f32_16x16x32_bf16(Am[kt][0], Bi[g][kt][0], ai[g], 0, 0, 0);
                ai[g] = __builtin_amdgcn_mfma_f32_16x16x32_bf16(Am[kt][0], Bi[g][kt][1], ai[g], 0, 0, 0);
                ai[g] = __builtin_amdgcn_mfma_f32_16x16x32_bf16(Am[kt][1], Bi[g][kt][0], ai[g], 0, 0, 0);
                ah[g] = __builtin_amdgcn_mfma_f32_16x16x32_bf16(Ah[kt][0], Bh[g][kt][0], ah[g], 0, 0, 0);
                ah[g] = __builtin_amdgcn_mfma_f32_16x16x32_bf16(Ah[kt][0], Bh[g][kt][1], ah[g], 0, 0, 0);
                ah[g] = __builtin_amdgcn_mfma_f32_16x16x32_bf16(Ah[kt][1], Bh[g][kt][0], ah[g], 0, 0, 0);
            }
        #pragma unroll
        for (int r = 0; r < 4; ++r) {
            int node = mt * 16 + quad * 4 + r;
            float rr = sigmoidf_(ai[0][r] + br_i + ah[0][r] + br_h);
            float zz = sigmoidf_(ai[1][r] + bz_i + ah[1][r] + bz_h);
            float n2 = tanhf(ai[2][r] + bn_i + rr * (ah[2][r] + bn_h));
            float hnew = (1.f - zz) * n2 + zz * h_s[node][f];
            int n = n0 + node;
            if (n < N_NODES) node_h[(size_t)n * 64 + f] = hnew;
            hn_s[node][f] = hnew;
        }
    }
    if (want_pack) {
        __syncthreads();
        for (int idx = tid; idx < 2048; idx += 256) {
            int tt = idx >> 10, r2 = idx & 1023;
            int kt = r2 >> 9, ln = (r2 >> 3) & 63, j = r2 & 7;
            int q2 = ln >> 4, mm = ln & 15;
            float v = hn_s[tt * 16 + mm][kt * 32 + q2 * 8 + j];
            unsigned short hi = f2bf(v);
            size_t base = (size_t)(blockIdx.x * 2 + tt) * 2048 + kt * 1024 + ln * 8 + j;
            Apack[base] = hi;
            Apack[base + 512] = f2bf(v - bf2f(hi));
        }
    }
}

// ---------------- Set2Set (3 steps) + output MLP, 256 threads (4 waves) per graph ---
__global__ __launch_bounds__(256)
void s2s_kernel(const float* __restrict__ node_h, const int* __restrict__ gptr,
                const float* __restrict__ WihT, const float* __restrict__ WhhT,
                const float* __restrict__ bih, const float* __restrict__ bhh,
                const float* __restrict__ o1W, const float* __restrict__ o1b,
                const float* __restrict__ o2W, const float* __restrict__ o2b,
                float* __restrict__ z) {
    int g = blockIdx.x, tid = threadIdx.x;
    int f = tid & 63, q = tid >> 6;
    __shared__ float qs[128], hs[64], qv[64], wts[256], gvs[4][64], racc_s[4][64];
    __shared__ float mred[4], sred[4], ored[2];
    if (q == 0) { qs[f] = 0.f; qs[64 + f] = 0.f; hs[f] = 0.f; }
    float c_t = 0.f;
    int nbeg = gptr[g], nend = gptr[g + 1];
    __syncthreads();
    for (int st = 0; st < 3; ++st) {
        {   // all 4 gates in parallel (one per wave)
            int row = q * 64 + f;
            float s = bih[row] + bhh[row];
            #pragma unroll 8
            for (int i = 0; i < 128; ++i) s += qs[i] * WihT[i * 256 + row];
            #pragma unroll 8
            for (int i = 0; i < 64; ++i) s += hs[i] * WhhT[i * 256 + row];
            gvs[q][f] = s;
        }
        __syncthreads();
        if (q == 0) {
            float c = sigmoidf_(gvs[1][f]) * c_t + sigmoidf_(gvs[0][f]) * tanhf(gvs[2][f]);
            float hn = sigmoidf_(gvs[3][f]) * tanhf(c);
            c_t = c;
            hs[f] = hn; qv[f] = hn;
        }
        __syncthreads();
        float rm = -INFINITY, rs = 0.f, raccl = 0.f;
        for (int base = nbeg; base < nend; base += 256) {
            int n = base + tid;
            float e = -INFINITY;
            if (n < nend) {
                float s = 0.f;
                #pragma unroll 8
                for (int ff = 0; ff < 64; ++ff) s += node_h[(size_t)n * 64 + ff] * qv[ff];
                e = s;
            }
            float cm = e;
            #pragma unroll
            for (int o = 32; o > 0; o >>= 1) cm = fmaxf(cm, __shfl_down(cm, o));
            if ((tid & 63) == 0) mred[q] = cm;
            __syncthreads();
            float bm = fmaxf(fmaxf(mred[0], mred[1]), fmaxf(mred[2], mred[3]));
            float nm = fmaxf(rm, bm);
            float scale = (rm == -INFINITY) ? 0.f : expf(rm - nm);
            float wv = (n < nend) ? expf(e - nm) : 0.f;
            wts[tid] = wv;
            float cs = wv;
            #pragma unroll
            for (int o = 32; o > 0; o >>= 1) cs += __shfl_down(cs, o);
            if ((tid & 63) == 0) sred[q] = cs;
            __syncthreads();
            float bs = (sred[0] + sred[1]) + (sred[2] + sred[3]);
            float na = raccl * scale;
            int cnt2 = min(256, nend - base);
            int l0 = q * 64, l1 = min(l0 + 64, cnt2);
            for (int l = l0; l < l1; ++l) na += wts[l] * node_h[(size_t)(base + l) * 64 + f];
            raccl = na;
            rs = rs * scale + bs;
            rm = nm;
            __syncthreads();
        }
        racc_s[q][f] = raccl;
        __syncthreads();
        if (q == 0) {
            float r = (nend > nbeg)
                    ? ((racc_s[0][f] + racc_s[1][f]) + (racc_s[2][f] + racc_s[3][f])) / rs
                    : 0.f;
            qs[f] = qv[f];
            qs[64 + f] = r;
        }
        __syncthreads();
    }
    if (tid < 128) {
        float sA = o1b[tid];
        #pragma unroll 8
        for (int i = 0; i < 128; ++i) sA += qs[i] * o1W[i * 128 + tid];
        float red = fmaxf(sA, 0.f) * o2W[tid];
        #pragma unroll
        for (int o = 32; o > 0; o >>= 1) red += __shfl_down(red, o);
        if ((tid & 63) == 0) ored[tid >> 6] = red;
    }
    __syncthreads();
    if (tid == 0) z[g] = ored[0] + ored[1] + o2b[0];
}

extern "C" void kernel_launch(void* const* d_in, const int* in_sizes, int n_in,
                              void* d_out, int out_size, void* d_ws, size_t ws_size,
                              hipStream_t stream) {
    const float* x         = (const float*)d_in[0];
    const float* edge_attr = (const float*)d_in[1];
    const int*   ei        = (const int*)d_in[2];
    const int*   batch     = (const int*)d_in[3];
    const float* in_W      = (const float*)d_in[4];
    const float* in_b      = (const float*)d_in[5];
    const float* e1_W      = (const float*)d_in[6];
    const float* e1_b      = (const float*)d_in[7];
    const float* e2_W      = (const float*)d_in[8];
    const float* e2_b      = (const float*)d_in[9];
    const float* conv_b    = (const float*)d_in[10];
    const float* gWih      = (const float*)d_in[11];
    const float* gWhh      = (const float*)d_in[12];
    const float* gbih      = (const float*)d_in[13];
    const float* gbhh      = (const float*)d_in[14];
    const float* lWih      = (const float*)d_in[15];
    const float* lWhh      = (const float*)d_in[16];
    const float* lbih      = (const float*)d_in[17];
    const float* lbhh      = (const float*)d_in[18];
    const float* o1W       = (const float*)d_in[19];
    const float* o1b       = (const float*)d_in[20];
    const float* o2W       = (const float*)d_in[21];
    const float* o2b       = (const float*)d_in[22];
    const int* src = ei;
    const int* dst = ei + N_EDGES;
    float* z = (float*)d_out;

    char* ws = (char*)d_ws;
    size_t off = 0;
    auto alloc = [&](size_t bytes) {
        void* p = ws + off;
        off = (off + bytes + 255) & ~(size_t)255;
        return p;
    };
    float* node_h   = (float*)alloc((size_t)N_NODES * 64 * 4);
    float* agg      = (float*)alloc((size_t)N_NODES * 64 * 4);
    float* h1       = (float*)alloc((size_t)N_EDGES * 64 * 4);
    unsigned short* Bhi = (unsigned short*)alloc((size_t)270336 * 2);
    unsigned short* Blo = (unsigned short*)alloc((size_t)270336 * 2);
    unsigned short* Apack = (unsigned short*)alloc((size_t)N_TILES_PAD * 2048 * 2);
    float* lWihT    = (float*)alloc(128 * 256 * 4);
    float* lWhhT    = (float*)alloc(64 * 256 * 4);
    unsigned short* gWihP = (unsigned short*)alloc(24576 * 2);
    unsigned short* gWhhP = (unsigned short*)alloc(24576 * 2);
    float* deg      = (float*)alloc(N_NODES * 4);       // deg,tcnt adjacent (one memset)
    int*   tcnt     = (int*)alloc((N_TILES + 2) * 4);
    int*   tcursor  = (int*)alloc((N_TILES + 2) * 4);
    int*   tptr     = (int*)alloc((N_TILES_PAD + 2) * 4);
    int*   edge_list= (int*)alloc(N_EDGES * 4);
    int*   gptr     = (int*)alloc((N_GRAPHS + 1) * 4);

    size_t degpad = ((size_t)N_NODES * 4 + 255) & ~(size_t)255;
    hipMemsetAsync(deg, 0, degpad + (N_TILES + 2) * 4, stream);   // deg + tcnt
    hipMemsetAsync(agg, 0, (size_t)N_NODES * 64 * 4, stream);     // once; gru re-zeroes

    prep_kernel<<<3748, 256, 0, stream>>>(x, in_W, in_b, node_h, e2_b,
                                          edge_attr, e1_W, e1_b, h1,
                                          e2_W, Bhi, Blo,
                                          lWih, lWhh, gWih, gWhh,
                                          lWihT, lWhhT, gWihP, gWhhP,
                                          batch, gptr, src, dst, tcnt, deg);
    tscan_kernel<<<1, 1024, 0, stream>>>(tcnt, tptr, tcursor);
    fillpack_kernel<<<157 + N_TILES_PAD, 256, 0, stream>>>(src, tcursor, edge_list,
                                                           node_h, Apack);

    for (int it = 0; it < 3; ++it) {
        conv_kernel<<<N_TILES_PAD * 8, 256, 0, stream>>>(Apack, h1, Bhi, Blo,
                                                         tptr, edge_list, src, dst, agg);
        gru_kernel<<<469, 256, 0, stream>>>(node_h, agg, deg, conv_b,
                                            gWihP, gWhhP, gbih, gbhh,
                                            Apack, (it < 2) ? 1 : 0);
    }
    s2s_kernel<<<N_GRAPHS, 256, 0, stream>>>(node_h, gptr, lWihT, lWhhT, lbih, lbhh,
                                             o1W, o1b, o2W, o2b, z);
}